// Round 9
// baseline (8522.426 us; speedup 1.0000x reference)
//
#include <hip/hip_runtime.h>
#include <hip/hip_bf16.h>

#define NU 50000
#define NI 100000
#define NROWS 150000
#define EMB 128

// Build ego = concat(user_emb, item_emb); also write output chunk 0 (raw ego, fp32).
__global__ __launch_bounds__(256) void k_concat(const float* __restrict__ ue,
                                                const float* __restrict__ ie,
                                                float* __restrict__ ego,
                                                float* __restrict__ out) {
    int idx = blockIdx.x * 256 + threadIdx.x;   // float4 index over NROWS*32
    if (idx >= NROWS * 32) return;
    int row = idx >> 5, q = idx & 31;
    float4 v = (row < NU) ? ((const float4*)ue)[(size_t)row * 32 + q]
                          : ((const float4*)ie)[(size_t)(row - NU) * 32 + q];
    ((float4*)ego)[idx] = v;
    ((float4*)(out + (size_t)row * 512))[q] = v;
}

// Pass 1: per-row degree count (no cap — exact CSR).
__global__ __launch_bounds__(256) void k_count(const int* __restrict__ rows,
                                               const int* __restrict__ cols,
                                               int* __restrict__ counts, int nnz) {
    int e = blockIdx.x * 256 + threadIdx.x;
    if (e >= nnz) return;
    unsigned int r = (unsigned int)rows[e];
    unsigned int c = (unsigned int)cols[e];
    if (r < NROWS && c < NROWS) atomicAdd(counts + r, 1);
}

// Exclusive prefix scan of counts -> row_start[NROWS+1]; also seeds cursor.
__global__ __launch_bounds__(1024) void k_scan(const int* __restrict__ counts,
                                               int* __restrict__ row_start,
                                               int* __restrict__ cursor) {
    __shared__ int s[1024];
    int tid = threadIdx.x;
    int base = 0;
    for (int i0 = 0; i0 < NROWS; i0 += 1024) {
        int i = i0 + tid;
        int c = (i < NROWS) ? counts[i] : 0;
        __syncthreads();              // protect s[] from previous iteration's readers
        s[tid] = c;
        __syncthreads();
        for (int off = 1; off < 1024; off <<= 1) {
            int v = (tid >= off) ? s[tid - off] : 0;
            __syncthreads();
            s[tid] += v;
            __syncthreads();
        }
        if (i < NROWS) {
            int excl = base + s[tid] - c;
            row_start[i] = excl;
            cursor[i] = excl;
        }
        base += s[1023];              // uniform (post-sync) chunk total
    }
    if (tid == 0) row_start[NROWS] = base;
}

// Pass 2: fill CSR (col, val) via per-row cursor.
__global__ __launch_bounds__(256) void k_fill(const int* __restrict__ rows,
                                              const int* __restrict__ cols,
                                              const float* __restrict__ vals,
                                              int* __restrict__ cursor,
                                              int2* __restrict__ csr, int nnz) {
    int e = blockIdx.x * 256 + threadIdx.x;
    if (e >= nnz) return;
    unsigned int r = (unsigned int)rows[e];
    unsigned int c = (unsigned int)cols[e];
    if (r >= NROWS || c >= NROWS) return;
    int pos = atomicAdd(cursor + r, 1);
    csr[pos] = make_int2((int)c, __float_as_int(vals[e]));
}

// side[row] = sum_e val_e * ego[col_e] over the row's CSR segment.
// Block per row; 4 waves stride the edge list; LDS combine. Handles any degree.
__global__ __launch_bounds__(256) void k_spmm_csr(const int* __restrict__ row_start,
                                                  const int2* __restrict__ csr,
                                                  const float* __restrict__ ego,
                                                  float* __restrict__ side) {
    int r = blockIdx.x;
    if (r >= NROWS) return;
    int s = row_start[r], e = row_start[r + 1];
    int wv = threadIdx.x >> 6, lane = threadIdx.x & 63;
    float ax = 0.f, ay = 0.f;
    for (int i = s + wv; i < e; i += 4) {
        int2 cv = csr[i];                              // uniform across wave
        float v = __int_as_float(cv.y);
        float2 eg = ((const float2*)(ego + (size_t)cv.x * EMB))[lane];
        ax += v * eg.x; ay += v * eg.y;
    }
    __shared__ float red[4][EMB];
    red[wv][2 * lane]     = ax;
    red[wv][2 * lane + 1] = ay;
    __syncthreads();
    if (threadIdx.x < EMB) {
        int d = threadIdx.x;
        side[(size_t)r * EMB + d] = red[0][d] + red[1][d] + red[2][d] + red[3][d];
    }
}

// Fused: lrelu(side@Wg+bg) + lrelu((ego.*side)@Wb+bb) -> new ego (in-place, fp32)
// and l2-normalized fp32 output chunk. 4 lanes per row, each owns 32 output cols.
__global__ __launch_bounds__(256) void k_gemm(const float* __restrict__ side,
                                              float* __restrict__ ego,
                                              const float* __restrict__ Wg,
                                              const float* __restrict__ bg,
                                              const float* __restrict__ Wb,
                                              const float* __restrict__ bb,
                                              float* __restrict__ out,
                                              int chunk) {
    int t = blockIdx.x * 256 + threadIdx.x;
    int row = t >> 2;
    int jg = t & 3;
    if (row >= NROWS) return;
    int j0 = jg * 32;
    float accg[32], accb[32];
#pragma unroll
    for (int j = 0; j < 32; ++j) { accg[j] = bg[j0 + j]; accb[j] = bb[j0 + j]; }
    const float* __restrict__ srow = side + (size_t)row * EMB;
    const float* __restrict__ erow = ego + (size_t)row * EMB;
#pragma unroll 1
    for (int k0 = 0; k0 < EMB; k0 += 4) {
        float4 s4 = *(const float4*)(srow + k0);
        float4 e4 = *(const float4*)(erow + k0);
        float ss[4] = {s4.x, s4.y, s4.z, s4.w};
        float ee[4] = {e4.x, e4.y, e4.z, e4.w};
#pragma unroll
        for (int kk = 0; kk < 4; ++kk) {
            float s = ss[kk];
            float es = s * ee[kk];
            const float4* __restrict__ wg4 = (const float4*)(Wg + (size_t)(k0 + kk) * EMB + j0);
            const float4* __restrict__ wb4 = (const float4*)(Wb + (size_t)(k0 + kk) * EMB + j0);
#pragma unroll
            for (int jq = 0; jq < 8; ++jq) {
                float4 wg = wg4[jq], wb = wb4[jq];
                accg[jq * 4 + 0] += s * wg.x;  accg[jq * 4 + 1] += s * wg.y;
                accg[jq * 4 + 2] += s * wg.z;  accg[jq * 4 + 3] += s * wg.w;
                accb[jq * 4 + 0] += es * wb.x; accb[jq * 4 + 1] += es * wb.y;
                accb[jq * 4 + 2] += es * wb.z; accb[jq * 4 + 3] += es * wb.w;
            }
        }
    }
    float nn[32];
#pragma unroll
    for (int j = 0; j < 32; ++j) {
        float g = accg[j]; g = g > 0.f ? g : 0.01f * g;
        float b = accb[j]; b = b > 0.f ? b : 0.01f * b;
        nn[j] = g + b;
    }
    // Overflow/underflow-safe l2 norm over the 128-wide row (4 lanes).
    float m = 0.f;
#pragma unroll
    for (int j = 0; j < 32; ++j) m = fmaxf(m, fabsf(nn[j]));
    m = fmaxf(m, __shfl_xor(m, 1));
    m = fmaxf(m, __shfl_xor(m, 2));
    float scale = (m > 0.f) ? 1.0f / m : 0.f;
    float ssum = 0.f;
#pragma unroll
    for (int j = 0; j < 32; ++j) { float z = nn[j] * scale; ssum += z * z; }
    ssum += __shfl_xor(ssum, 1);
    ssum += __shfl_xor(ssum, 2);
    float norm = m * sqrtf(ssum);
    float inv = 1.0f / fmaxf(norm, 1e-12f);
    float* eo = ego + (size_t)row * EMB + j0;
#pragma unroll
    for (int j = 0; j < 8; ++j)
        ((float4*)eo)[j] = make_float4(nn[j*4], nn[j*4+1], nn[j*4+2], nn[j*4+3]);
    float* o = out + (size_t)row * 512 + chunk * EMB + j0;
#pragma unroll
    for (int j = 0; j < 8; ++j)
        ((float4*)o)[j] = make_float4(nn[j*4] * inv, nn[j*4+1] * inv,
                                      nn[j*4+2] * inv, nn[j*4+3] * inv);
}

extern "C" void kernel_launch(void* const* d_in, const int* in_sizes, int n_in,
                              void* d_out, int out_size, void* d_ws, size_t ws_size,
                              hipStream_t stream) {
    const float* ue  = (const float*)d_in[0];
    const float* ie  = (const float*)d_in[1];
    const float* gw  = (const float*)d_in[2];
    const float* gb  = (const float*)d_in[3];
    const float* bw  = (const float*)d_in[4];
    const float* bbp = (const float*)d_in[5];
    const int*   ar  = (const int*)d_in[6];
    const int*   ac  = (const int*)d_in[7];
    const float* av  = (const float*)d_in[8];
    float* out = (float*)d_out;
    int nnz = in_sizes[6];

    char* ws = (char*)d_ws;
    float* ego      = (float*)(ws);                    // 76,800,000 B
    float* side     = (float*)(ws + 76800000);         // 76,800,000 B
    int*   counts   = (int*)(ws + 153600000);          //    600,000 B
    int*   row_start= (int*)(ws + 154200000);          //    600,004 B
    int*   cursor   = (int*)(ws + 154800004);          //    600,000 B
    int2*  csr      = (int2*)(ws + 155400004);         // 16,000,000 B  (tot ~171.4 MB)

    hipMemsetAsync(counts, 0, NROWS * sizeof(int), stream);
    k_concat<<<(NROWS * 32 + 255) / 256, 256, 0, stream>>>(ue, ie, ego, out);
    k_count<<<(nnz + 255) / 256, 256, 0, stream>>>(ar, ac, counts, nnz);
    k_scan<<<1, 1024, 0, stream>>>(counts, row_start, cursor);
    k_fill<<<(nnz + 255) / 256, 256, 0, stream>>>(ar, ac, av, cursor, csr, nnz);
    for (int i = 0; i < 3; ++i) {
        k_spmm_csr<<<NROWS, 256, 0, stream>>>(row_start, csr, ego, side);
        k_gemm<<<(NROWS * 4 + 255) / 256, 256, 0, stream>>>(
            side, ego, gw + (size_t)i * EMB * EMB, gb + (size_t)i * EMB,
            bw + (size_t)i * EMB * EMB, bbp + (size_t)i * EMB, out, i + 1);
    }
}

// Round 11
// 2681.677 us; speedup vs baseline: 3.1780x; 3.1780x over previous
//
#include <hip/hip_runtime.h>
#include <hip/hip_bf16.h>

#define NU 50000
#define NI 100000
#define NROWS 150000
#define EMB 128

// Build ego = concat(user_emb, item_emb); also write output chunk 0 (raw ego, fp32).
__global__ __launch_bounds__(256) void k_concat(const float* __restrict__ ue,
                                                const float* __restrict__ ie,
                                                float* __restrict__ ego,
                                                float* __restrict__ out) {
    int idx = blockIdx.x * 256 + threadIdx.x;   // float4 index over NROWS*32
    if (idx >= NROWS * 32) return;
    int row = idx >> 5, q = idx & 31;
    float4 v = (row < NU) ? ((const float4*)ue)[(size_t)row * 32 + q]
                          : ((const float4*)ie)[(size_t)(row - NU) * 32 + q];
    ((float4*)ego)[idx] = v;
    ((float4*)(out + (size_t)row * 512))[q] = v;
}

// Pass 1: per-row degree count (no cap — exact CSR).
__global__ __launch_bounds__(256) void k_count(const int* __restrict__ rows,
                                               const int* __restrict__ cols,
                                               int* __restrict__ counts, int nnz) {
    int e = blockIdx.x * 256 + threadIdx.x;
    if (e >= nnz) return;
    unsigned int r = (unsigned int)rows[e];
    unsigned int c = (unsigned int)cols[e];
    if (r < NROWS && c < NROWS) atomicAdd(counts + r, 1);
}

// Exclusive prefix scan of counts -> row_start[NROWS+1]; also seeds cursor.
__global__ __launch_bounds__(1024) void k_scan(const int* __restrict__ counts,
                                               int* __restrict__ row_start,
                                               int* __restrict__ cursor) {
    __shared__ int s[1024];
    int tid = threadIdx.x;
    int base = 0;
    for (int i0 = 0; i0 < NROWS; i0 += 1024) {
        int i = i0 + tid;
        int c = (i < NROWS) ? counts[i] : 0;
        __syncthreads();              // protect s[] from previous iteration's readers
        s[tid] = c;
        __syncthreads();
        for (int off = 1; off < 1024; off <<= 1) {
            int v = (tid >= off) ? s[tid - off] : 0;
            __syncthreads();
            s[tid] += v;
            __syncthreads();
        }
        if (i < NROWS) {
            int excl = base + s[tid] - c;
            row_start[i] = excl;
            cursor[i] = excl;
        }
        base += s[1023];              // uniform (post-sync) chunk total
    }
    if (tid == 0) row_start[NROWS] = base;
}

// Pass 2: fill CSR (col, val) via per-row cursor.
__global__ __launch_bounds__(256) void k_fill(const int* __restrict__ rows,
                                              const int* __restrict__ cols,
                                              const float* __restrict__ vals,
                                              int* __restrict__ cursor,
                                              int2* __restrict__ csr, int nnz) {
    int e = blockIdx.x * 256 + threadIdx.x;
    if (e >= nnz) return;
    unsigned int r = (unsigned int)rows[e];
    unsigned int c = (unsigned int)cols[e];
    if (r >= NROWS || c >= NROWS) return;
    int pos = atomicAdd(cursor + r, 1);
    csr[pos] = make_int2((int)c, __float_as_int(vals[e]));
}

// side[row] = sum_e val_e * ego[col_e] over the row's CSR segment.
// Block per row; 4 waves stride the edge list; LDS combine. Handles any degree.
__global__ __launch_bounds__(256) void k_spmm_csr(const int* __restrict__ row_start,
                                                  const int2* __restrict__ csr,
                                                  const float* __restrict__ ego,
                                                  float* __restrict__ side) {
    int r = blockIdx.x;
    if (r >= NROWS) return;
    int s = row_start[r], e = row_start[r + 1];
    int wv = threadIdx.x >> 6, lane = threadIdx.x & 63;
    float ax = 0.f, ay = 0.f;
    for (int i = s + wv; i < e; i += 4) {
        int2 cv = csr[i];                              // uniform across wave
        float v = __int_as_float(cv.y);
        float2 eg = ((const float2*)(ego + (size_t)cv.x * EMB))[lane];
        ax += v * eg.x; ay += v * eg.y;
    }
    __shared__ float red[4][EMB];
    red[wv][2 * lane]     = ax;
    red[wv][2 * lane + 1] = ay;
    __syncthreads();
    if (threadIdx.x < EMB) {
        int d = threadIdx.x;
        side[(size_t)r * EMB + d] = red[0][d] + red[1][d] + red[2][d] + red[3][d];
    }
}

// Fused dual-GEMM + lrelu + add + l2norm. Register-tiled:
// block = 32 rows x 128 cols; thread (tc=tid&31, tr=tid>>5) owns 4 rows x 4 cols
// of BOTH branches (32 accumulators). __launch_bounds__(256,4) => 128-VGPR cap.
__global__ __launch_bounds__(256, 4) void k_gemm(const float* __restrict__ side,
                                                 float* __restrict__ ego,
                                                 const float* __restrict__ Wg,
                                                 const float* __restrict__ bg,
                                                 const float* __restrict__ Wb,
                                                 const float* __restrict__ bb,
                                                 float* __restrict__ out,
                                                 int chunk) {
    const int tid = threadIdx.x;
    const int tc = tid & 31;          // owns cols [4*tc, 4*tc+4)
    const int tr = tid >> 5;          // owns rows [row0, row0+4)
    const int row0 = blockIdx.x * 32 + tr * 4;
    const int j0 = tc * 4;

    float accg[4][4], accb[4][4];
    const float4 bgv = *(const float4*)(bg + j0);
    const float4 bbv = *(const float4*)(bb + j0);
#pragma unroll
    for (int r = 0; r < 4; ++r) {
        accg[r][0] = bgv.x; accg[r][1] = bgv.y; accg[r][2] = bgv.z; accg[r][3] = bgv.w;
        accb[r][0] = bbv.x; accb[r][1] = bbv.y; accb[r][2] = bbv.z; accb[r][3] = bbv.w;
    }
    const float* sp[4];
    const float* ep[4];
#pragma unroll
    for (int r = 0; r < 4; ++r) {
        int rr = row0 + r; if (rr > NROWS - 1) rr = NROWS - 1;  // clamp loads; stores guarded
        sp[r] = side + (size_t)rr * EMB;
        ep[r] = ego + (size_t)rr * EMB;
    }

#pragma unroll 1
    for (int k = 0; k < EMB; k += 4) {
        float4 wg[4], wb[4];
#pragma unroll
        for (int i = 0; i < 4; ++i) {
            wg[i] = *(const float4*)(Wg + (size_t)(k + i) * EMB + j0);
            wb[i] = *(const float4*)(Wb + (size_t)(k + i) * EMB + j0);
        }
#pragma unroll
        for (int r = 0; r < 4; ++r) {
            float4 sv = *(const float4*)(sp[r] + k);
            float4 ev = *(const float4*)(ep[r] + k);
            float s, es;
            s = sv.x; es = s * ev.x;
            accg[r][0] += s * wg[0].x; accg[r][1] += s * wg[0].y;
            accg[r][2] += s * wg[0].z; accg[r][3] += s * wg[0].w;
            accb[r][0] += es * wb[0].x; accb[r][1] += es * wb[0].y;
            accb[r][2] += es * wb[0].z; accb[r][3] += es * wb[0].w;
            s = sv.y; es = s * ev.y;
            accg[r][0] += s * wg[1].x; accg[r][1] += s * wg[1].y;
            accg[r][2] += s * wg[1].z; accg[r][3] += s * wg[1].w;
            accb[r][0] += es * wb[1].x; accb[r][1] += es * wb[1].y;
            accb[r][2] += es * wb[1].z; accb[r][3] += es * wb[1].w;
            s = sv.z; es = s * ev.z;
            accg[r][0] += s * wg[2].x; accg[r][1] += s * wg[2].y;
            accg[r][2] += s * wg[2].z; accg[r][3] += s * wg[2].w;
            accb[r][0] += es * wb[2].x; accb[r][1] += es * wb[2].y;
            accb[r][2] += es * wb[2].z; accb[r][3] += es * wb[2].w;
            s = sv.w; es = s * ev.w;
            accg[r][0] += s * wg[3].x; accg[r][1] += s * wg[3].y;
            accg[r][2] += s * wg[3].z; accg[r][3] += s * wg[3].w;
            accb[r][0] += es * wb[3].x; accb[r][1] += es * wb[3].y;
            accb[r][2] += es * wb[3].z; accb[r][3] += es * wb[3].w;
        }
    }

#pragma unroll
    for (int r = 0; r < 4; ++r) {
        float nn[4];
        float ss = 0.f;
#pragma unroll
        for (int c = 0; c < 4; ++c) {
            float g = accg[r][c]; g = g > 0.f ? g : 0.01f * g;
            float b = accb[r][c]; b = b > 0.f ? b : 0.01f * b;
            float v = g + b; nn[c] = v; ss += v * v;
        }
        // row-sum across the 32 col-threads (lanes differing in bits 0..4 only)
        ss += __shfl_xor(ss, 1);
        ss += __shfl_xor(ss, 2);
        ss += __shfl_xor(ss, 4);
        ss += __shfl_xor(ss, 8);
        ss += __shfl_xor(ss, 16);
        float inv = 1.0f / fmaxf(sqrtf(ss), 1e-12f);
        int rr = row0 + r;
        if (rr < NROWS) {
            *(float4*)(ego + (size_t)rr * EMB + j0) =
                make_float4(nn[0], nn[1], nn[2], nn[3]);
            *(float4*)(out + (size_t)rr * 512 + chunk * EMB + j0) =
                make_float4(nn[0] * inv, nn[1] * inv, nn[2] * inv, nn[3] * inv);
        }
    }
}

extern "C" void kernel_launch(void* const* d_in, const int* in_sizes, int n_in,
                              void* d_out, int out_size, void* d_ws, size_t ws_size,
                              hipStream_t stream) {
    const float* ue  = (const float*)d_in[0];
    const float* ie  = (const float*)d_in[1];
    const float* gw  = (const float*)d_in[2];
    const float* gb  = (const float*)d_in[3];
    const float* bw  = (const float*)d_in[4];
    const float* bbp = (const float*)d_in[5];
    const int*   ar  = (const int*)d_in[6];
    const int*   ac  = (const int*)d_in[7];
    const float* av  = (const float*)d_in[8];
    float* out = (float*)d_out;
    int nnz = in_sizes[6];

    char* ws = (char*)d_ws;
    float* ego      = (float*)(ws);                    // 76,800,000 B
    float* side     = (float*)(ws + 76800000);         // 76,800,000 B
    int*   counts   = (int*)(ws + 153600000);          //    600,000 B
    int*   row_start= (int*)(ws + 154200000);          //    600,004 B
    int*   cursor   = (int*)(ws + 154800004);          //    600,000 B
    int2*  csr      = (int2*)(ws + 155400004);         // 16,000,000 B  (tot ~171.4 MB)

    hipMemsetAsync(counts, 0, NROWS * sizeof(int), stream);
    k_concat<<<(NROWS * 32 + 255) / 256, 256, 0, stream>>>(ue, ie, ego, out);
    k_count<<<(nnz + 255) / 256, 256, 0, stream>>>(ar, ac, counts, nnz);
    k_scan<<<1, 1024, 0, stream>>>(counts, row_start, cursor);
    k_fill<<<(nnz + 255) / 256, 256, 0, stream>>>(ar, ac, av, cursor, csr, nnz);
    const int gemm_blocks = (NROWS + 31) / 32;
    for (int i = 0; i < 3; ++i) {
        k_spmm_csr<<<NROWS, 256, 0, stream>>>(row_start, csr, ego, side);
        k_gemm<<<gemm_blocks, 256, 0, stream>>>(
            side, ego, gw + (size_t)i * EMB * EMB, gb + (size_t)i * EMB,
            bw + (size_t)i * EMB * EMB, bbp + (size_t)i * EMB, out, i + 1);
    }
}